// Round 5
// baseline (211.436 us; speedup 1.0000x reference)
//
#include <hip/hip_runtime.h>
#include <math.h>

// NetVLAD clustering layer, f32, MI355X — 3 kernels.
// x:[16,256,1500], centroids:[64,256], lin_w:[66,256], lin_b:[66]
// out: [16, 64*256] f32
//
// KA (chunk,u) 256 thr, 1 block/CU, TCH=96, t-PAIR register blocking:
//   lane owns t=(2l,2l+1) as float2 -> each W ds_read_b128 broadcast feeds
//   2 t's (halves the LDS-pipe load that bound round 2), v_pk_fma_f32 math.
//   Logits: 4-wave f-quarter split, W staged in 2 halves (4 barriers);
//   reduce via ds_add_f32 atomics into zeroed Buf; ALL-wave parallel softmax
//   (redundant per wave, each wave writes a 16-c slice of Asm).
//   Agg: 8c x 8f per thread over 48 float2 t-pairs.
// KB (cq,u): one wave per c; float4 coalesced loads; shuffle-only reduce.
// KC: global L2 scale (float4).

#define NU 16
#define NF 256
#define NT 1500
#define NC 64
#define NCG 66          // clusters + ghosts
#define EPSN 1e-12f
#define TCH 96          // t-chunk (16 chunks cover 1536 >= 1500)
#define NCHUNK 16

typedef float v2f __attribute__((ext_vector_type(2)));

// LDS layout (floats), total 40004 f = 160,016 B (fits 160 KiB, 1 block/CU):
//   Xsm [256][98]   @ 0      (25088)  rows 8B-aligned -> float2 ok
//   Wsm [4][66][32] @ 25088  ( 8448)  rows 128B -> float4 ok
//   Buf [66][96]    @ 33536  ( 6336)  union with
//   Asm [66][98]    @ 33536  ( 6468)
#define S_XSM 0
#define S_WSM 25088
#define S_BUF 33536
#define S_TOTAL 40004

// ---------------- KA: logits + softmax + per-chunk aggregation ----------------
__global__ __launch_bounds__(256, 1) void ka_fused(
        const float* __restrict__ x, const float* __restrict__ lin_w,
        const float* __restrict__ lin_b, float* __restrict__ partial,
        float* __restrict__ asum_part) {
    __shared__ float S[S_TOTAL];
    float* Xsm  = S + S_XSM;
    float* Wsm  = S + S_WSM;
    float* Buf  = S + S_BUF;
    float* Asm_ = S + S_BUF;

    const int chunk = blockIdx.x, u = blockIdx.y;
    const int tid = threadIdx.x, lane = tid & 63, wave = tid >> 6;
    const int t0 = chunk * TCH;

    // ---- phase 1: stage X chunk -> LDS (zero-fill past NT) + zero Buf ----
    {
        const int fr = tid >> 2;          // f row 0..63 (+64r)
        const int ks = (tid & 3) * 4;     // t offset 0,4,8,12
        #pragma unroll
        for (int r = 0; r < 4; ++r) {
            const int f = fr + 64 * r;
            const float* rp = x + (size_t)(u * NF + f) * NT + t0;
            #pragma unroll
            for (int q = 0; q < 6; ++q) {
                const int kk = ks + 16 * q;        // 0..92, covers 96
                const int tg = t0 + kk;
                float4 v;
                if (tg + 3 < NT) v = *(const float4*)(rp + kk);  // 16B-aligned
                else {
                    v.x = (tg + 0 < NT) ? rp[kk + 0] : 0.0f;
                    v.y = (tg + 1 < NT) ? rp[kk + 1] : 0.0f;
                    v.z = (tg + 2 < NT) ? rp[kk + 2] : 0.0f;
                    v.w = (tg + 3 < NT) ? rp[kk + 3] : 0.0f;
                }
                *(v2f*)&Xsm[f * 98 + kk]     = (v2f){v.x, v.y};
                *(v2f*)&Xsm[f * 98 + kk + 2] = (v2f){v.z, v.w};
            }
        }
        for (int i = tid; i < NCG * 96; i += 256) Buf[i] = 0.0f;
    }
    __syncthreads();

    // ---- logits: wave w = f-quarter [64w,64w+64); lane owns t-pair 2l,2l+1 ----
    const int lp = (lane < 48) ? lane : 47;   // lanes 48-63 duplicate pair 47
    v2f acc[NCG];
    #pragma unroll
    for (int c = 0; c < NCG; ++c) acc[c] = (v2f){0.0f, 0.0f};

    #pragma unroll
    for (int half = 0; half < 2; ++half) {
        // stage Wsm[wave][c][k] = lin_w[c][wave*64 + half*32 + k], k<32
        {
            const int fb = wave * 64 + half * 32;
            for (int idx = lane; idx < NCG * 32; idx += 64) {
                const int c = idx >> 5, k = idx & 31;
                Wsm[(wave * NCG + c) * 32 + k] = lin_w[c * NF + fb + k];
            }
        }
        __syncthreads();
        #pragma unroll
        for (int fc = 0; fc < 2; ++fc) {
            const int fbase = wave * 64 + half * 32 + fc * 16;
            v2f xv[16];
            #pragma unroll
            for (int k = 0; k < 16; ++k)
                xv[k] = *(const v2f*)&Xsm[(fbase + k) * 98 + 2 * lp];
            #pragma unroll
            for (int c = 0; c < NCG; ++c) {
                const float4* wp = (const float4*)&Wsm[(wave * NCG + c) * 32 + fc * 16];
                const float4 w0 = wp[0], w1 = wp[1], w2 = wp[2], w3 = wp[3];
                v2f a = acc[c];
                a += xv[0]  * w0.x; a += xv[1]  * w0.y; a += xv[2]  * w0.z; a += xv[3]  * w0.w;
                a += xv[4]  * w1.x; a += xv[5]  * w1.y; a += xv[6]  * w1.z; a += xv[7]  * w1.w;
                a += xv[8]  * w2.x; a += xv[9]  * w2.y; a += xv[10] * w2.z; a += xv[11] * w2.w;
                a += xv[12] * w3.x; a += xv[13] * w3.y; a += xv[14] * w3.z; a += xv[15] * w3.w;
                acc[c] = a;
            }
        }
        if (half == 0) __syncthreads();   // before restaging Wsm
    }

    // ---- cross-wave reduce: ds_add_f32 atomics into zeroed Buf ----
    if (lane < 48) {
        #pragma unroll
        for (int c = 0; c < NCG; ++c) {
            atomicAdd(&Buf[c * 96 + 2 * lp],     acc[c].x);
            atomicAdd(&Buf[c * 96 + 2 * lp + 1], acc[c].y);
        }
    }
    __syncthreads();

    // ---- all-wave parallel softmax (each wave redundantly, own lanes) ----
    float sA, sB;
    {
        #pragma unroll
        for (int c = 0; c < NCG; ++c) {
            const v2f l = *(const v2f*)&Buf[c * 96 + 2 * lp];
            const float b = lin_b[c];                 // uniform -> s_load
            acc[c] = (v2f){l.x + b, l.y + b};
        }
        v2f m = acc[0];
        #pragma unroll
        for (int c = 1; c < NCG; ++c) {
            m.x = fmaxf(m.x, acc[c].x);
            m.y = fmaxf(m.y, acc[c].y);
        }
        v2f s = (v2f){0.0f, 0.0f};
        #pragma unroll
        for (int c = 0; c < NCG; ++c) {
            acc[c].x = __expf(acc[c].x - m.x);
            acc[c].y = __expf(acc[c].y - m.y);
            s += acc[c];
        }
        const int tA = t0 + 2 * lp, tB = tA + 1;
        sA = (tA < NT) ? (1.0f / s.x) : 0.0f;         // zero padded t's
        sB = (tB < NT) ? (1.0f / s.y) : 0.0f;
    }
    __syncthreads();                                   // Buf reads done

    // wave q writes Asm rows c in [16q, 16q+16)  (overwrites Buf region)
    if (lane < 48) {
        const int cw = wave * 16;
        #pragma unroll
        for (int i = 0; i < 16; ++i) {
            const int c = cw + i;
            *(v2f*)&Asm_[c * 98 + 2 * lp] = (v2f){acc[c].x * sA, acc[c].y * sB};
        }
    }
    __syncthreads();

    // ---- aggregation: 8c x 8f per thread, 48 float2 t-pairs ----
    {
        const int cb = (tid >> 5) * 8;   // 8 half-wave groups x 8 c
        const int fl = tid & 31;         // f = fl + 32j
        v2f ag[8][8], as[8];
        #pragma unroll
        for (int i = 0; i < 8; ++i) {
            as[i] = (v2f){0.0f, 0.0f};
            #pragma unroll
            for (int j = 0; j < 8; ++j) ag[i][j] = (v2f){0.0f, 0.0f};
        }

        for (int kp = 0; kp < TCH / 2; ++kp) {
            v2f av[8], xv[8];
            #pragma unroll
            for (int i = 0; i < 8; ++i)
                av[i] = *(const v2f*)&Asm_[(cb + i) * 98 + 2 * kp];   // broadcast
            #pragma unroll
            for (int j = 0; j < 8; ++j)
                xv[j] = *(const v2f*)&Xsm[(fl + 32 * j) * 98 + 2 * kp]; // 2-way=free
            #pragma unroll
            for (int i = 0; i < 8; ++i) {
                as[i] += av[i];
                #pragma unroll
                for (int j = 0; j < 8; ++j) ag[i][j] += av[i] * xv[j];
            }
        }

        #pragma unroll
        for (int i = 0; i < 8; ++i) {
            float* op = partial + ((size_t)((chunk * NU + u) * NC + cb + i)) * NF;
            #pragma unroll
            for (int j = 0; j < 8; ++j) op[fl + 32 * j] = ag[i][j].x + ag[i][j].y;
        }
        if (fl == 0) {
            #pragma unroll
            for (int i = 0; i < 8; ++i)
                asum_part[(chunk * NU + u) * NC + cb + i] = as[i].x + as[i].y;
        }
    }
}

// ---------------- KB: reduce partials + intra-normalize (wave per c) --------
__global__ __launch_bounds__(256) void kb_norm(
        const float* __restrict__ asum_part, const float* __restrict__ partial,
        const float* __restrict__ centroids, float* __restrict__ compn,
        float* __restrict__ rowsq) {
    const int u = blockIdx.y;
    const int wave = threadIdx.x >> 6, lane = threadIdx.x & 63;
    const int c = blockIdx.x * 4 + wave;         // grid.x = 16 -> c in [0,64)

    float asum = 0.0f;                           // wave-uniform -> scalar loads
    #pragma unroll
    for (int ch = 0; ch < NCHUNK; ++ch)
        asum += asum_part[(ch * NU + u) * NC + c];

    float4 val = make_float4(0.f, 0.f, 0.f, 0.f);
    #pragma unroll
    for (int ch = 0; ch < NCHUNK; ++ch) {
        const float4 p = *(const float4*)(
            partial + ((size_t)((ch * NU + u) * NC + c)) * NF + lane * 4);
        val.x += p.x; val.y += p.y; val.z += p.z; val.w += p.w;
    }
    const float4 ce = *(const float4*)(centroids + c * NF + lane * 4);
    val.x -= asum * ce.x; val.y -= asum * ce.y;
    val.z -= asum * ce.z; val.w -= asum * ce.w;

    float ss = val.x * val.x + val.y * val.y + val.z * val.z + val.w * val.w;
    #pragma unroll
    for (int off = 32; off > 0; off >>= 1) ss += __shfl_down(ss, off, 64);
    ss = __shfl(ss, 0, 64);                      // broadcast total

    const float d   = fmaxf(sqrtf(ss), EPSN);
    const float inv = 1.0f / d;
    float4 o;
    o.x = val.x * inv; o.y = val.y * inv; o.z = val.z * inv; o.w = val.w * inv;
    *(float4*)(compn + ((size_t)(u * NC + c)) * NF + lane * 4) = o;
    if (lane == 0) rowsq[u * NC + c] = ss / (d * d);
}

// ---------------- KC: global normalize ----------------
__global__ __launch_bounds__(256) void kc_scale(
        const float* __restrict__ compn, const float* __restrict__ rowsq,
        float* __restrict__ out) {
    const int u = blockIdx.y, sl = blockIdx.x;
    const int tid = threadIdx.x;
    float g = 0.0f;                      // uniform -> scalar loads
    #pragma unroll
    for (int c = 0; c < NC; ++c) g += rowsq[u * NC + c];
    const float inv = 1.0f / fmaxf(sqrtf(g), EPSN);
    const int base = u * (NC * NF) + sl * 1024 + tid * 4;
    float4 v = *(const float4*)(compn + base);
    v.x *= inv; v.y *= inv; v.z *= inv; v.w *= inv;
    *(float4*)(out + base) = v;
}

// ---------------- launcher ----------------
extern "C" void kernel_launch(void* const* d_in, const int* in_sizes, int n_in,
                              void* d_out, int out_size, void* d_ws, size_t ws_size,
                              hipStream_t stream) {
    (void)in_sizes; (void)n_in; (void)out_size; (void)ws_size;
    const float* x         = (const float*)d_in[0];
    const float* centroids = (const float*)d_in[1];
    const float* lin_w     = (const float*)d_in[2];
    const float* lin_b     = (const float*)d_in[3];
    float* out = (float*)d_out;

    float* ws        = (float*)d_ws;
    float* partial   = ws;                                        // 16*16*64*256 = 4,194,304 f
    float* asum_part = partial + (size_t)NCHUNK * NU * NC * NF;   // 16*16*64 = 16,384 f
    float* compn     = asum_part + NCHUNK * NU * NC;              // 262,144 f
    float* rowsq     = compn + (size_t)NU * NC * NF;              // 1,024 f (~17.9 MB)

    dim3 blk(256);
    hipLaunchKernelGGL(ka_fused, dim3(NCHUNK, NU), blk, 0, stream,
                       x, lin_w, lin_b, partial, asum_part);
    hipLaunchKernelGGL(kb_norm,  dim3(16, NU), blk, 0, stream,
                       asum_part, partial, centroids, compn, rowsq);
    hipLaunchKernelGGL(kc_scale, dim3(16, NU), blk, 0, stream,
                       compn, rowsq, out);
}